// Round 1
// baseline (1047.546 us; speedup 1.0000x reference)
//
#include <hip/hip_runtime.h>

#define TINV 0.125f  // 1/TEMPERATURE
constexpr int S = 1024;
constexpr int D = 64;

// ---------------- Kernel A: logits1 = (q/T) @ k^T  (written to attn region) ----
// grid (8 j-tiles, 8 i-tiles, 16 bh), block 256
__global__ __launch_bounds__(256) void k_attn1(const float* __restrict__ q,
                                               const float* __restrict__ k,
                                               float* __restrict__ attn) {
  __shared__ float Qs[128][36];  // pad 36: stride mod 32 = 4 -> conflict-free-ish b128
  __shared__ float Ks[128][36];
  const int z  = blockIdx.z;          // b*8+h
  const int i0 = blockIdx.y * 128;
  const int j0 = blockIdx.x * 128;
  const int t  = threadIdx.x;
  const int tx = t & 15;
  const int ty = t >> 4;

  const float4* qsrc = (const float4*)(q + ((size_t)z * S + i0) * D);
  const float4* ksrc = (const float4*)(k + ((size_t)z * S + j0) * D);

  float acc[8][8];
#pragma unroll
  for (int r = 0; r < 8; ++r)
#pragma unroll
    for (int c = 0; c < 8; ++c) acc[r][c] = 0.f;

#pragma unroll
  for (int p = 0; p < 2; ++p) {       // two halves of the d=64 dimension
    if (p) __syncthreads();
#pragma unroll
    for (int it = 0; it < 4; ++it) {
      int fidx = t + it * 256;        // 0..1023 float4 slots, 8 per row
      int row  = fidx >> 3;
      int c8   = fidx & 7;
      float4 qv = qsrc[row * 16 + p * 8 + c8];
      qv.x *= TINV; qv.y *= TINV; qv.z *= TINV; qv.w *= TINV;
      *(float4*)&Qs[row][c8 * 4] = qv;
      *(float4*)&Ks[row][c8 * 4] = ksrc[row * 16 + p * 8 + c8];
    }
    __syncthreads();
#pragma unroll
    for (int dc = 0; dc < 8; ++dc) {
      float4 kf[8];
#pragma unroll
      for (int c = 0; c < 8; ++c) kf[c] = *(const float4*)&Ks[tx + 16 * c][dc * 4];
#pragma unroll
      for (int r = 0; r < 8; ++r) {
        const float4 qf = *(const float4*)&Qs[ty + 16 * r][dc * 4];
#pragma unroll
        for (int c = 0; c < 8; ++c) {
          acc[r][c] += qf.x * kf[c].x + qf.y * kf[c].y + qf.z * kf[c].z + qf.w * kf[c].w;
        }
      }
    }
  }

  float* dst = attn + ((size_t)z * S + i0) * S + j0;
#pragma unroll
  for (int r = 0; r < 8; ++r)
#pragma unroll
    for (int c = 0; c < 8; ++c)
      dst[(size_t)(ty + 16 * r) * S + tx + 16 * c] = acc[r][c];
}

// ---------------- Kernel B: += (q/T)@rpr^T, mask, softmax (in-place on attn) --
// grid (1024 i, 2 b), block 256
__global__ __launch_bounds__(256) void k_attn2_softmax(const float* __restrict__ q,
                                                       const float* __restrict__ rpr,
                                                       const int* __restrict__ mask,
                                                       float* __restrict__ attn) {
  __shared__ float qsh[8][64];
  __shared__ float logits[8][1024];
  __shared__ float redA[4][8];
  __shared__ float redB[4][8];

  const int i    = blockIdx.x;
  const int b    = blockIdx.y;
  const int t    = threadIdx.x;
  const int lane = t & 63;
  const int wid  = t >> 6;

  // stage q[b,:,i,:]/T  (8 heads x 64) into LDS
  if (t < 128) {
    int h  = t >> 4;
    int c4 = t & 15;
    const float4* src = (const float4*)(q + (((size_t)b * 8 + h) * S + i) * D);
    float4 v = src[c4];
    v.x *= TINV; v.y *= TINV; v.z *= TINV; v.w *= TINV;
    *(float4*)&qsh[h][c4 * 4] = v;
  }
  __syncthreads();

  const float4* rsrc   = (const float4*)(rpr + ((size_t)b * S + i) * (size_t)S * D);
  const float*  a1base = attn + ((size_t)b * 8 * S + i) * S;  // + h*S*S + j
  const int*    mrow   = mask + ((size_t)b * S + i) * S;

  // phase 1: stream rpr rows, accumulate all 8 heads, fold attn1 + mask -> LDS
  for (int jt = 0; jt < 4; ++jt) {
    const int j = t + jt * 256;
    const float4* rrow = rsrc + (size_t)j * 16;
    float acc_h[8];
#pragma unroll
    for (int h = 0; h < 8; ++h) acc_h[h] = 0.f;
#pragma unroll
    for (int half = 0; half < 2; ++half) {
      float4 rv[8];
#pragma unroll
      for (int u = 0; u < 8; ++u) rv[u] = rrow[half * 8 + u];  // 8 outstanding b128
#pragma unroll
      for (int u = 0; u < 8; ++u) {
        const int dc = half * 8 + u;
#pragma unroll
        for (int h = 0; h < 8; ++h) {
          const float4 qv = *(const float4*)&qsh[h][dc * 4];  // wave-broadcast read
          acc_h[h] += rv[u].x * qv.x + rv[u].y * qv.y + rv[u].z * qv.z + rv[u].w * qv.w;
        }
      }
    }
    const int m = mrow[j];
#pragma unroll
    for (int h = 0; h < 8; ++h) {
      float val = acc_h[h] + a1base[(size_t)h * S * S + j];
      logits[h][j] = (m == 0) ? -1e9f : val;
    }
  }

  // phase 2: softmax per head row (own LDS writes are same-thread ordered)
  float lg[8][4];
#pragma unroll
  for (int h = 0; h < 8; ++h)
#pragma unroll
    for (int jt = 0; jt < 4; ++jt) lg[h][jt] = logits[h][t + jt * 256];

  float rmax[8];
#pragma unroll
  for (int h = 0; h < 8; ++h) {
    float m = fmaxf(fmaxf(lg[h][0], lg[h][1]), fmaxf(lg[h][2], lg[h][3]));
#pragma unroll
    for (int off = 32; off >= 1; off >>= 1) m = fmaxf(m, __shfl_xor(m, off));
    if (lane == 0) redA[wid][h] = m;
  }
  __syncthreads();
#pragma unroll
  for (int h = 0; h < 8; ++h)
    rmax[h] = fmaxf(fmaxf(redA[0][h], redA[1][h]), fmaxf(redA[2][h], redA[3][h]));

  float rsum[8];
#pragma unroll
  for (int h = 0; h < 8; ++h) {
#pragma unroll
    for (int jt = 0; jt < 4; ++jt) lg[h][jt] = __expf(lg[h][jt] - rmax[h]);
    float s = lg[h][0] + lg[h][1] + lg[h][2] + lg[h][3];
#pragma unroll
    for (int off = 32; off >= 1; off >>= 1) s += __shfl_xor(s, off);
    if (lane == 0) redB[wid][h] = s;
  }
  __syncthreads();
#pragma unroll
  for (int h = 0; h < 8; ++h)
    rsum[h] = redB[0][h] + redB[1][h] + redB[2][h] + redB[3][h];

  float* adst = attn + ((size_t)b * 8 * S + i) * S;
#pragma unroll
  for (int h = 0; h < 8; ++h) {
    const float inv = 1.0f / rsum[h];
#pragma unroll
    for (int jt = 0; jt < 4; ++jt)
      adst[(size_t)h * S * S + t + jt * 256] = lg[h][jt] * inv;
  }
}

// ---------------- Kernel C: output = attn @ v --------------------------------
// grid (16 i-tiles, 16 bh), block 256
__global__ __launch_bounds__(256) void k_pv(const float* __restrict__ attn,
                                            const float* __restrict__ v,
                                            float* __restrict__ out) {
  __shared__ float Ps[64][68];
  __shared__ float Vs[64][68];
  const int bh = blockIdx.y;
  const int i0 = blockIdx.x * 64;
  const int t  = threadIdx.x;
  const int tx = t & 15;
  const int ty = t >> 4;

  float acc[4][4];
#pragma unroll
  for (int r = 0; r < 4; ++r)
#pragma unroll
    for (int c = 0; c < 4; ++c) acc[r][c] = 0.f;

  const float*  abase = attn + ((size_t)bh * S + i0) * S;
  const float4* vbase = (const float4*)(v + (size_t)bh * S * D);

  for (int jt = 0; jt < 16; ++jt) {
    if (jt) __syncthreads();
    const int j0 = jt * 64;
#pragma unroll
    for (int it = 0; it < 4; ++it) {
      int fidx = t + it * 256;      // 64 rows x 16 float4
      int row  = fidx >> 4;
      int c4   = fidx & 15;
      *(float4*)&Ps[row][c4 * 4] = *(const float4*)(abase + (size_t)row * S + j0 + c4 * 4);
      *(float4*)&Vs[row][c4 * 4] = vbase[(size_t)(j0 + row) * 16 + c4];
    }
    __syncthreads();
#pragma unroll
    for (int jc = 0; jc < 16; ++jc) {
      float vr[4][4];
#pragma unroll
      for (int jj = 0; jj < 4; ++jj) {
        float4 tv = *(const float4*)&Vs[jc * 4 + jj][tx * 4];
        vr[jj][0] = tv.x; vr[jj][1] = tv.y; vr[jj][2] = tv.z; vr[jj][3] = tv.w;
      }
#pragma unroll
      for (int r = 0; r < 4; ++r) {
        float4 pf = *(const float4*)&Ps[ty + 16 * r][jc * 4];
        float pa[4] = {pf.x, pf.y, pf.z, pf.w};
#pragma unroll
        for (int c = 0; c < 4; ++c) {
#pragma unroll
          for (int jj = 0; jj < 4; ++jj) acc[r][c] += pa[jj] * vr[jj][c];
        }
      }
    }
  }

  float* obase = out + (size_t)bh * S * D;
#pragma unroll
  for (int r = 0; r < 4; ++r) {
    float4 st = make_float4(acc[r][0], acc[r][1], acc[r][2], acc[r][3]);
    *(float4*)(obase + (size_t)(i0 + ty + 16 * r) * D + tx * 4) = st;
  }
}

extern "C" void kernel_launch(void* const* d_in, const int* in_sizes, int n_in,
                              void* d_out, int out_size, void* d_ws, size_t ws_size,
                              hipStream_t stream) {
  const float* q    = (const float*)d_in[0];
  const float* k    = (const float*)d_in[1];
  const float* v    = (const float*)d_in[2];
  const int*   mask = (const int*)d_in[3];
  const float* rpr  = (const float*)d_in[4];

  float* out  = (float*)d_out;                    // (2,8,1024,64)
  float* attn = out + (size_t)2 * 8 * S * D;      // (2,8,1024,1024), also logits scratch

  hipLaunchKernelGGL(k_attn1,         dim3(8, 8, 16), dim3(256), 0, stream, q, k, attn);
  hipLaunchKernelGGL(k_attn2_softmax, dim3(1024, 2),  dim3(256), 0, stream, q, rpr, mask, attn);
  hipLaunchKernelGGL(k_pv,            dim3(16, 16),   dim3(256), 0, stream, attn, v, out);
}